// Round 1
// baseline (130.987 us; speedup 1.0000x reference)
//
#include <hip/hip_runtime.h>
#include <hip/hip_bf16.h>
#include <stdint.h>

#define NB 4
#define NT 2048
#define NC 1024
#define NH 128
#define ND 8
#define NTOK (NB*NT)      // 8192 tokens
#define GK 1024           // GEMM K
#define GN 1024           // GEMM N

typedef __attribute__((ext_vector_type(4))) float f32x4;
typedef __attribute__((ext_vector_type(8))) short bf16x8;

#define GLOAD_LDS16(g, l) \
  __builtin_amdgcn_global_load_lds((const __attribute__((address_space(1))) void*)(g), \
                                   (__attribute__((address_space(3))) void*)(l), 16, 0, 0)

// float -> bf16 RTNE (finite inputs only)
__device__ __forceinline__ unsigned short f2bf(float f) {
  unsigned u = __float_as_uint(f);
  u += 0x7FFFu + ((u >> 16) & 1u);
  return (unsigned short)(u >> 16);
}

// ---------------- W fp32 -> bf16 ----------------
__global__ __launch_bounds__(256) void wconv_kernel(const float4* __restrict__ w,
                                                    ushort4* __restrict__ wb) {
  int i = blockIdx.x * 256 + threadIdx.x;   // over 1048576/4 elements
  float4 v = w[i];
  ushort4 o;
  o.x = f2bf(v.x); o.y = f2bf(v.y); o.z = f2bf(v.z); o.w = f2bf(v.w);
  wb[i] = o;
}

// ---------------- per-token attention ----------------
// One block = one token (128 heads). Thread h owns head h.
// q = cos(x + S); scores bounded by sqrt(8) => softmax without max-subtraction.
__global__ __launch_bounds__(128) void attn_kernel(const float* __restrict__ x,
                                                   const float* __restrict__ theta,
                                                   unsigned short* __restrict__ aout) {
  __shared__ __align__(16) float q[NH][ND];   // 4 KB
  const int tok = blockIdx.x;
  const int h = threadIdx.x;

  float S = 0.f;
#pragma unroll
  for (int j = 0; j < ND; ++j) S += theta[j];

  const float* xr = x + (size_t)tok * NC + h * ND;
  float4 xa = *(const float4*)xr;
  float4 xb = *(const float4*)(xr + 4);
  float qh[8];
  qh[0] = cosf(xa.x + S); qh[1] = cosf(xa.y + S);
  qh[2] = cosf(xa.z + S); qh[3] = cosf(xa.w + S);
  qh[4] = cosf(xb.x + S); qh[5] = cosf(xb.y + S);
  qh[6] = cosf(xb.z + S); qh[7] = cosf(xb.w + S);
#pragma unroll
  for (int j = 0; j < ND; ++j) q[h][j] = qh[j];
  __syncthreads();

  float qs[8];
#pragma unroll
  for (int j = 0; j < 8; ++j) qs[j] = qh[j] * 0.35355339059327373f; // 1/sqrt(8)

  float l = 0.f;
  float acc[8] = {0.f, 0.f, 0.f, 0.f, 0.f, 0.f, 0.f, 0.f};
#pragma unroll 4
  for (int g = 0; g < NH; ++g) {
    float4 a = *(const float4*)&q[g][0];    // broadcast LDS reads (free)
    float4 b = *(const float4*)&q[g][4];
    float s = qs[0]*a.x + qs[1]*a.y + qs[2]*a.z + qs[3]*a.w
            + qs[4]*b.x + qs[5]*b.y + qs[6]*b.z + qs[7]*b.w;
    float p = __expf(s);                    // s in [-2.83, 2.83] -> safe
    l += p;
    acc[0] += p*a.x; acc[1] += p*a.y; acc[2] += p*a.z; acc[3] += p*a.w;
    acc[4] += p*b.x; acc[5] += p*b.y; acc[6] += p*b.z; acc[7] += p*b.w;
  }
  float inv = 1.0f / l;

  uint4 ov;
  ov.x = (unsigned)f2bf(acc[0]*inv) | ((unsigned)f2bf(acc[1]*inv) << 16);
  ov.y = (unsigned)f2bf(acc[2]*inv) | ((unsigned)f2bf(acc[3]*inv) << 16);
  ov.z = (unsigned)f2bf(acc[4]*inv) | ((unsigned)f2bf(acc[5]*inv) << 16);
  ov.w = (unsigned)f2bf(acc[6]*inv) | ((unsigned)f2bf(acc[7]*inv) << 16);
  *reinterpret_cast<uint4*>(aout + (size_t)tok * NC + h * ND) = ov;
}

// ---------------- projection GEMM: y[M,N] = A[M,K] * Bt[N,K]^T ----------------
// m97 structure: 128x128 tile, BK=32, 4 waves (2x2), 4x4 16x16x32 bf16 MFMA,
// global_load_lds width 16, linear LDS.
#define BM 128
#define BN 128
#define BK 32

__global__ __launch_bounds__(256) void gemm_kernel(const unsigned short* __restrict__ A,
                                                   const unsigned short* __restrict__ Bt,
                                                   float* __restrict__ C) {
  __shared__ __align__(16) unsigned short As[BM * BK];  // 8 KB
  __shared__ __align__(16) unsigned short Bs[BN * BK];  // 8 KB

  const int bm = blockIdx.x;
  const int bn = blockIdx.y;
  const int tid = (int)threadIdx.x;
  const int lane = tid & 63;
  const int w = tid >> 6;        // wave 0..3
  const int wm = w >> 1;         // 0..1 over M
  const int wn = w & 1;          // 0..1 over N

  f32x4 acc[4][4] = {};

  // staging: each wave stages 32 rows of A and B (2 x global_load_lds of 1KB)
  const int sr = w * 32 + (lane >> 2);     // row within tile
  const int sc = (lane & 3) * 8;           // k-offset within tile
  const unsigned short* gA = A + (size_t)(bm * BM + sr) * GK + sc;
  const unsigned short* gB = Bt + (size_t)(bn * BN + sr) * GK + sc;
  unsigned short* lA = &As[(w * 32) * BK]; // wave-uniform LDS base
  unsigned short* lB = &Bs[(w * 32) * BK];

  const int fr = lane & 15;                // fragment row
  const int fk = (lane >> 4) * 8;          // fragment k-offset

  for (int kt = 0; kt < GK; kt += BK) {
    __syncthreads();                       // previous compute done
    GLOAD_LDS16(gA, lA);
    GLOAD_LDS16(gA + 16 * GK, lA + 16 * BK);
    GLOAD_LDS16(gB, lB);
    GLOAD_LDS16(gB + 16 * GK, lB + 16 * BK);
    asm volatile("s_waitcnt vmcnt(0)" ::: "memory");
    __syncthreads();

    bf16x8 af[4], bfr[4];
#pragma unroll
    for (int i = 0; i < 4; ++i)
      af[i] = *reinterpret_cast<const bf16x8*>(&As[(wm * 64 + i * 16 + fr) * BK + fk]);
#pragma unroll
    for (int j = 0; j < 4; ++j)
      bfr[j] = *reinterpret_cast<const bf16x8*>(&Bs[(wn * 64 + j * 16 + fr) * BK + fk]);

#pragma unroll
    for (int i = 0; i < 4; ++i)
#pragma unroll
      for (int j = 0; j < 4; ++j)
        acc[i][j] = __builtin_amdgcn_mfma_f32_16x16x32_bf16(af[i], bfr[j], acc[i][j], 0, 0, 0);

    gA += BK;
    gB += BK;
  }

  // C/D layout: col = lane&15, row = (lane>>4)*4 + reg  [m89/m91 verified]
  float* Cb = C + (size_t)(bm * BM + wm * 64) * GN + bn * BN + wn * 64;
  const int cr = (lane >> 4) * 4;
  const int cc = lane & 15;
#pragma unroll
  for (int i = 0; i < 4; ++i)
#pragma unroll
    for (int j = 0; j < 4; ++j)
#pragma unroll
      for (int r = 0; r < 4; ++r)
        Cb[(size_t)(i * 16 + cr + r) * GN + j * 16 + cc] = acc[i][j][r];
}

extern "C" void kernel_launch(void* const* d_in, const int* in_sizes, int n_in,
                              void* d_out, int out_size, void* d_ws, size_t ws_size,
                              hipStream_t stream) {
  (void)in_sizes; (void)n_in; (void)out_size; (void)ws_size;
  const float* x = (const float*)d_in[0];
  const float* theta = (const float*)d_in[1];
  const float* wproj = (const float*)d_in[2];
  float* y = (float*)d_out;

  // ws layout: [0,16MB) attn output bf16 [NTOK][NC]; [16MB,18MB) W bf16 [NC][NC]
  unsigned short* attn_out = (unsigned short*)d_ws;
  unsigned short* wb = (unsigned short*)((char*)d_ws + (size_t)NTOK * NC * 2);

  wconv_kernel<<<(NC * NC / 4) / 256, 256, 0, stream>>>((const float4*)wproj,
                                                        (ushort4*)wb);
  attn_kernel<<<NTOK, 128, 0, stream>>>(x, theta, attn_out);
  dim3 grid(NTOK / BM, GN / BN);
  gemm_kernel<<<grid, 256, 0, stream>>>(attn_out, wb, y);
}

// Round 2
// 75.183 us; speedup vs baseline: 1.7423x; 1.7423x over previous
//
#include <hip/hip_runtime.h>
#include <hip/hip_bf16.h>
#include <stdint.h>

#define NB 4
#define NT 2048
#define NC 1024
#define NH 128
#define ND 8
#define NTOK (NB*NT)      // 8192 tokens
#define GK 1024           // GEMM K
#define GN 1024           // GEMM N

typedef __attribute__((ext_vector_type(4))) float f32x4;
typedef __attribute__((ext_vector_type(8))) short bf16x8;
typedef unsigned int uint32;

#define GLOAD_LDS16(g, l) \
  __builtin_amdgcn_global_load_lds((const __attribute__((address_space(1))) void*)(g), \
                                   (__attribute__((address_space(3))) void*)(l), 16, 0, 0)

// float -> bf16 RTNE via native cast (lowers to v_cvt[_pk]_bf16_f32 on gfx950)
__device__ __forceinline__ unsigned short f2bf(float f) {
  __bf16 b = (__bf16)f;
  return __builtin_bit_cast(unsigned short, b);
}

// ---------------- W fp32 -> bf16 ----------------
__global__ __launch_bounds__(256) void wconv_kernel(const float4* __restrict__ w,
                                                    ushort4* __restrict__ wb) {
  int i = blockIdx.x * 256 + threadIdx.x;
  float4 v = w[i];
  ushort4 o;
  o.x = f2bf(v.x); o.y = f2bf(v.y); o.z = f2bf(v.z); o.w = f2bf(v.w);
  wb[i] = o;
}

// ---------------- per-token attention via MFMA ----------------
// One block = one token. 256 threads = 4 waves; wave w owns S rows 32w..32w+31.
// Q_lds [128][40]: cols 0..7 = q (bf16), col 8 = 1.0 (ones trick: adds uniform
//   +1 to scores -> softmax-invariant; and PV output col 8 = row-sum), 9..31 = 0.
// E is symmetric (S=QQ^T), so C/D-layout's 4 consecutive rows per lane store
//   as one contiguous b64 write at E[col][row0..row0+3].
#define QSTR 40     // 80B row stride: 16B-aligned, 2-way bank pattern
#define ESTR 136    // 272B row stride: 16B-aligned, even bank spread

__global__ __launch_bounds__(256) void attn_kernel(const float* __restrict__ x,
                                                   const float* __restrict__ theta,
                                                   unsigned short* __restrict__ aout) {
  __shared__ __align__(16) unsigned short Q[NH * QSTR];    // 10.0 KB
  __shared__ __align__(16) unsigned short QTm[16 * ESTR];  //  4.3 KB
  __shared__ __align__(16) unsigned short E[NH * ESTR];    // 34.0 KB

  const int tok = blockIdx.x;
  const int tid = (int)threadIdx.x;

  float S = 0.f;
#pragma unroll
  for (int j = 0; j < ND; ++j) S += theta[j];

  // ---- phase 0: q = cos(x + S), write Q (row-major, padded) and QT ----
  {
    const int r = tid >> 1, h = tid & 1;
    float4 xv = *(const float4*)(x + (size_t)tok * NC + r * ND + h * 4);
    unsigned short b0 = f2bf(__cosf(xv.x + S));
    unsigned short b1 = f2bf(__cosf(xv.y + S));
    unsigned short b2 = f2bf(__cosf(xv.z + S));
    unsigned short b3 = f2bf(__cosf(xv.w + S));
    uint2 pk;
    pk.x = (uint32)b0 | ((uint32)b1 << 16);
    pk.y = (uint32)b2 | ((uint32)b3 << 16);
    *(uint2*)&Q[r * QSTR + h * 4] = pk;
    if (h == 0) {
      uint4 onev = {0x3F80u, 0u, 0u, 0u};          // col8 = 1.0bf16, 9..15 = 0
      *(uint4*)&Q[r * QSTR + 8] = onev;
    } else {
      uint4 z = {0u, 0u, 0u, 0u};                  // cols 16..31 = 0
      *(uint4*)&Q[r * QSTR + 16] = z;
      *(uint4*)&Q[r * QSTR + 24] = z;
    }
    QTm[(4 * h + 0) * ESTR + r] = b0;
    QTm[(4 * h + 1) * ESTR + r] = b1;
    QTm[(4 * h + 2) * ESTR + r] = b2;
    QTm[(4 * h + 3) * ESTR + r] = b3;
    if (h == 1) QTm[8 * ESTR + r] = 0x3F80u;       // ones row -> rowsum col
#pragma unroll
    for (int z2 = tid; z2 < 7 * 128; z2 += 256)    // zero QT rows 9..15
      QTm[(9 + (z2 >> 7)) * ESTR + (z2 & 127)] = 0;
  }
  __syncthreads();

  const int w = tid >> 6, l = tid & 63;
  const int fr = l & 15, fg = l >> 4;
  const float K1 = 0.51011859f;                    // log2(e)/sqrt(8)

  // ---- phase 1: S = Q.Q^T (+1), E = exp2(S*K1), store E^T-contiguous ----
  {
    bf16x8 aq0 = *(const bf16x8*)&Q[(32 * w + fr) * QSTR + fg * 8];
    bf16x8 aq1 = *(const bf16x8*)&Q[(32 * w + 16 + fr) * QSTR + fg * 8];
#pragma unroll
    for (int tj = 0; tj < 8; ++tj) {
      bf16x8 bq = *(const bf16x8*)&Q[(16 * tj + fr) * QSTR + fg * 8];
      f32x4 zero = {0.f, 0.f, 0.f, 0.f};
      f32x4 s0 = __builtin_amdgcn_mfma_f32_16x16x32_bf16(aq0, bq, zero, 0, 0, 0);
      f32x4 s1 = __builtin_amdgcn_mfma_f32_16x16x32_bf16(aq1, bq, zero, 0, 0, 0);
      uint2 e0, e1;
      {
        unsigned short p0 = f2bf(__builtin_amdgcn_exp2f(s0[0] * K1));
        unsigned short p1 = f2bf(__builtin_amdgcn_exp2f(s0[1] * K1));
        unsigned short p2 = f2bf(__builtin_amdgcn_exp2f(s0[2] * K1));
        unsigned short p3 = f2bf(__builtin_amdgcn_exp2f(s0[3] * K1));
        e0.x = (uint32)p0 | ((uint32)p1 << 16);
        e0.y = (uint32)p2 | ((uint32)p3 << 16);
        p0 = f2bf(__builtin_amdgcn_exp2f(s1[0] * K1));
        p1 = f2bf(__builtin_amdgcn_exp2f(s1[1] * K1));
        p2 = f2bf(__builtin_amdgcn_exp2f(s1[2] * K1));
        p3 = f2bf(__builtin_amdgcn_exp2f(s1[3] * K1));
        e1.x = (uint32)p0 | ((uint32)p1 << 16);
        e1.y = (uint32)p2 | ((uint32)p3 << 16);
      }
      const int c = 16 * tj + fr;                  // E^T store: col -> row
      *(uint2*)&E[c * ESTR + 32 * w + fg * 4] = e0;
      *(uint2*)&E[c * ESTR + 32 * w + 16 + fg * 4] = e1;
    }
  }
  __syncthreads();

  // ---- phase 2: O = P.[Q|1], normalize by col-8 rowsum, store bf16 ----
  {
    f32x4 o0 = {0.f, 0.f, 0.f, 0.f}, o1 = {0.f, 0.f, 0.f, 0.f};
#pragma unroll
    for (int ks = 0; ks < 4; ++ks) {
      bf16x8 bv = *(const bf16x8*)&QTm[fr * ESTR + ks * 32 + fg * 8];
      bf16x8 a0 = *(const bf16x8*)&E[(32 * w + fr) * ESTR + ks * 32 + fg * 8];
      bf16x8 a1 = *(const bf16x8*)&E[(32 * w + 16 + fr) * ESTR + ks * 32 + fg * 8];
      o0 = __builtin_amdgcn_mfma_f32_16x16x32_bf16(a0, bv, o0, 0, 0, 0);
      o1 = __builtin_amdgcn_mfma_f32_16x16x32_bf16(a1, bv, o1, 0, 0, 0);
    }
    const int src = (l & 48) | 8;                  // lane holding col 8 (rowsum)
    unsigned short* orow = aout + (size_t)tok * NC;
#pragma unroll
    for (int r = 0; r < 4; ++r) {
      float rs0 = __shfl(o0[r], src, 64);
      float rs1 = __shfl(o1[r], src, 64);
      if (fr < 8) {
        const int h0 = 32 * w + fg * 4 + r;
        orow[h0 * ND + fr] = f2bf(o0[r] * __builtin_amdgcn_rcpf(rs0));
        orow[(h0 + 16) * ND + fr] = f2bf(o1[r] * __builtin_amdgcn_rcpf(rs1));
      }
    }
  }
}

// ---------------- projection GEMM: y[M,N] = A[M,K] * Bt[N,K]^T ----------------
#define BM 128
#define BN 128
#define BK 32

__global__ __launch_bounds__(256) void gemm_kernel(const unsigned short* __restrict__ A,
                                                   const unsigned short* __restrict__ Bt,
                                                   float* __restrict__ C) {
  __shared__ __align__(16) unsigned short As[BM * BK];
  __shared__ __align__(16) unsigned short Bs[BN * BK];

  const int bm = blockIdx.x;
  const int bn = blockIdx.y;
  const int tid = (int)threadIdx.x;
  const int lane = tid & 63;
  const int w = tid >> 6;
  const int wm = w >> 1;
  const int wn = w & 1;

  f32x4 acc[4][4] = {};

  const int sr = w * 32 + (lane >> 2);
  const int sc = (lane & 3) * 8;
  const unsigned short* gA = A + (size_t)(bm * BM + sr) * GK + sc;
  const unsigned short* gB = Bt + (size_t)(bn * BN + sr) * GK + sc;
  unsigned short* lA = &As[(w * 32) * BK];
  unsigned short* lB = &Bs[(w * 32) * BK];

  const int fr = lane & 15;
  const int fk = (lane >> 4) * 8;

  for (int kt = 0; kt < GK; kt += BK) {
    __syncthreads();
    GLOAD_LDS16(gA, lA);
    GLOAD_LDS16(gA + 16 * GK, lA + 16 * BK);
    GLOAD_LDS16(gB, lB);
    GLOAD_LDS16(gB + 16 * GK, lB + 16 * BK);
    asm volatile("s_waitcnt vmcnt(0)" ::: "memory");
    __syncthreads();

    bf16x8 af[4], bfr[4];
#pragma unroll
    for (int i = 0; i < 4; ++i)
      af[i] = *reinterpret_cast<const bf16x8*>(&As[(wm * 64 + i * 16 + fr) * BK + fk]);
#pragma unroll
    for (int j = 0; j < 4; ++j)
      bfr[j] = *reinterpret_cast<const bf16x8*>(&Bs[(wn * 64 + j * 16 + fr) * BK + fk]);

#pragma unroll
    for (int i = 0; i < 4; ++i)
#pragma unroll
      for (int j = 0; j < 4; ++j)
        acc[i][j] = __builtin_amdgcn_mfma_f32_16x16x32_bf16(af[i], bfr[j], acc[i][j], 0, 0, 0);

    gA += BK;
    gB += BK;
  }

  float* Cb = C + (size_t)(bm * BM + wm * 64) * GN + bn * BN + wn * 64;
  const int cr = (lane >> 4) * 4;
  const int cc = lane & 15;
#pragma unroll
  for (int i = 0; i < 4; ++i)
#pragma unroll
    for (int j = 0; j < 4; ++j)
#pragma unroll
      for (int r = 0; r < 4; ++r)
        Cb[(size_t)(i * 16 + cr + r) * GN + j * 16 + cc] = acc[i][j][r];
}

extern "C" void kernel_launch(void* const* d_in, const int* in_sizes, int n_in,
                              void* d_out, int out_size, void* d_ws, size_t ws_size,
                              hipStream_t stream) {
  (void)in_sizes; (void)n_in; (void)out_size; (void)ws_size;
  const float* x = (const float*)d_in[0];
  const float* theta = (const float*)d_in[1];
  const float* wproj = (const float*)d_in[2];
  float* y = (float*)d_out;

  unsigned short* attn_out = (unsigned short*)d_ws;                       // 16 MB bf16
  unsigned short* wb = (unsigned short*)((char*)d_ws + (size_t)NTOK * NC * 2); // 2 MB bf16

  wconv_kernel<<<(NC * NC / 4) / 256, 256, 0, stream>>>((const float4*)wproj,
                                                        (ushort4*)wb);
  attn_kernel<<<NTOK, 256, 0, stream>>>(x, theta, attn_out);
  dim3 grid(NTOK / BM, GN / BN);
  gemm_kernel<<<grid, 256, 0, stream>>>(attn_out, wb, y);
}

// Round 5
// 69.187 us; speedup vs baseline: 1.8932x; 1.0867x over previous
//
#include <hip/hip_runtime.h>
#include <hip/hip_bf16.h>
#include <stdint.h>

#define NB 4
#define NT 2048
#define NC 1024
#define NH 128
#define ND 8
#define NTOK (NB*NT)      // 8192 tokens
#define GK 1024           // GEMM K
#define GN 1024           // GEMM N

typedef __attribute__((ext_vector_type(4))) float f32x4;
typedef __attribute__((ext_vector_type(8))) short bf16x8;
typedef __attribute__((ext_vector_type(4))) unsigned int u32x4;
typedef __attribute__((ext_vector_type(2))) unsigned int u32x2;
typedef unsigned int uint32;

// GAMMA = sqrt(log2(e)/sqrt(8)) folded into q' so exp2(S) needs no scale:
//   S = (GAMMA*cos)·(GAMMA*cos) summed = log2(e)/sqrt(8) * qq  -> exp2(S) = exp(qq/sqrt(8)).
// GB16 = bf16 0x3F37 = 0.71484375: PV ones-column value carrying the rowsum.
// C0 = GAMMA / 0.71484375 corrects the output/rowsum scale ratio.
#define GAMMA  0.71419167f
#define GB16   0x3F37u
#define C0     0.9990878f

#define GLOAD_LDS16(g, l) \
  __builtin_amdgcn_global_load_lds((const __attribute__((address_space(1))) void*)(g), \
                                   (__attribute__((address_space(3))) void*)(l), 16, 0, 0)

__device__ __forceinline__ unsigned short f2bf(float f) {
  __bf16 b = (__bf16)f;
  return __builtin_bit_cast(unsigned short, b);
}
__device__ __forceinline__ uint32 pk2(float a, float b) {   // bf16 pair, a in low
  return (uint32)f2bf(a) | ((uint32)f2bf(b) << 16);
}

// ---------------- W fp32 -> bf16 ----------------
__global__ __launch_bounds__(256) void wconv_kernel(const float4* __restrict__ w,
                                                    ushort4* __restrict__ wb) {
  int i = blockIdx.x * 256 + threadIdx.x;
  float4 v = w[i];
  ushort4 o;
  o.x = f2bf(v.x); o.y = f2bf(v.y); o.z = f2bf(v.z); o.w = f2bf(v.w);
  wb[i] = o;
}

// ---- per-token attention: 1 wave/token, 16x16x32 MFMA only (verified maps) --
// Verified fragment maps (gemm_kernel + R2, both passed on HW):
//   A/B: lane l -> row/col l&15, k-slots (l>>4)*8 + e (e=0..7)
//   C/D: lane l reg r -> m=(l>>4)*4+r, n=l&15
// S-operands under sigma_S(8t+e)= 2t+e (e<2, else dead): lane (c,t) supplies
//   its own dims 2t,2t+1 of rows 16a+c -> S = full 8-dim dot, no cross-lane.
// S symmetric => S-block(a,b) reg r at lane(c,t) = P[16b+c][16a+4t+r]:
//   row = c = A-fragment row => packed p-pairs of blocks (2j,2j+1) ARE the
//   PV A-fragment under sigma_j(8t+e) = 32j + 4t + (e&3) + 16*(e>>2).
// PV B reads sigma_j-permuted QT rows from LDS; cols 8..15 = GB16 (rowsum).
#define QTS 136   // QT row stride (elements); 272B rows spread banks

__global__ __launch_bounds__(256) void attn_kernel(const float* __restrict__ x,
                                                   const float* __restrict__ theta,
                                                   unsigned short* __restrict__ aout) {
  __shared__ __align__(16) unsigned short QT[4][8 * QTS];   // 8704 B total

  const int tid = (int)threadIdx.x;
  const int wid = tid >> 6;
  const int tok = blockIdx.x * 4 + wid;
  const int l = tid & 63;
  const int c = l & 15;
  const int t = l >> 4;

  float S = 0.f;
#pragma unroll
  for (int j = 0; j < ND; ++j) S += theta[j];

  // Load x: lane (c,t) owns rows 16a+c, dims 2t,2t+1 (wave tiles 512B/a).
  // q' = GAMMA*cos(x+S) -> S-fragment word0; QT[dim][g] for the PV B side.
  u32x4 qf[8];
  unsigned short* qt = &QT[wid][0];
#pragma unroll
  for (int a = 0; a < 8; ++a) {
    float2 xv = *(const float2*)(x + (size_t)tok * NC + (16 * a + c) * ND + 2 * t);
    float q0 = GAMMA * __cosf(xv.x + S);
    float q1 = GAMMA * __cosf(xv.y + S);
    unsigned short b0 = f2bf(q0), b1 = f2bf(q1);
    qt[(2 * t) * QTS + 16 * a + c] = b0;
    qt[(2 * t + 1) * QTS + 16 * a + c] = b1;
    qf[a].x = (uint32)b0 | ((uint32)b1 << 16);
    qf[a].y = 0u; qf[a].z = 0u; qf[a].w = 0u;
  }

  // PV B-fragments (shared by all 8 row-blocks): element e of frag j =
  //   Vext[32j + 4t + (e&3) + 16*(e>>2)][c];  cols c>=8 -> GB16 ones.
  u32x4 bff[4];
  {
    const int cm = (c < 8) ? c : 7;
    const bool isq = (c < 8);
    const uint32 onepair = GB16 | (GB16 << 16);
#pragma unroll
    for (int j = 0; j < 4; ++j) {
      u32x2 v0 = *(const u32x2*)&qt[cm * QTS + 32 * j + 4 * t];
      u32x2 v1 = *(const u32x2*)&qt[cm * QTS + 32 * j + 16 + 4 * t];
      bff[j].x = isq ? v0.x : onepair;
      bff[j].y = isq ? v0.y : onepair;
      bff[j].z = isq ? v1.x : onepair;
      bff[j].w = isq ? v1.y : onepair;
    }
  }

  const f32x4 z4 = {0.f, 0.f, 0.f, 0.f};
  unsigned short* orow = aout + (size_t)tok * NC;

#pragma unroll
  for (int b = 0; b < 8; ++b) {        // P-row block: rows 16b..16b+15
    f32x4 o = z4;
#pragma unroll
    for (int j = 0; j < 4; ++j) {      // g-chunk 32j..32j+31
      f32x4 sv0 = __builtin_amdgcn_mfma_f32_16x16x32_bf16(
          __builtin_bit_cast(bf16x8, qf[2 * j]), __builtin_bit_cast(bf16x8, qf[b]),
          z4, 0, 0, 0);
      f32x4 sv1 = __builtin_amdgcn_mfma_f32_16x16x32_bf16(
          __builtin_bit_cast(bf16x8, qf[2 * j + 1]), __builtin_bit_cast(bf16x8, qf[b]),
          z4, 0, 0, 0);
      // p = exp2(S); lane(c,t) reg r: sv0 -> P[16b+c][32j+4t+r],
      //                               sv1 -> P[16b+c][32j+16+4t+r]
      u32x4 af;
      af.x = pk2(__builtin_amdgcn_exp2f(sv0[0]), __builtin_amdgcn_exp2f(sv0[1]));
      af.y = pk2(__builtin_amdgcn_exp2f(sv0[2]), __builtin_amdgcn_exp2f(sv0[3]));
      af.z = pk2(__builtin_amdgcn_exp2f(sv1[0]), __builtin_amdgcn_exp2f(sv1[1]));
      af.w = pk2(__builtin_amdgcn_exp2f(sv1[2]), __builtin_amdgcn_exp2f(sv1[3]));
      o = __builtin_amdgcn_mfma_f32_16x16x32_bf16(
          __builtin_bit_cast(bf16x8, af), __builtin_bit_cast(bf16x8, bff[j]),
          o, 0, 0, 0);
    }
    // o reg r = O'[16b+4t+r][c]; rowsum*GB16 sits at col c+8 (lane l^8, same reg)
#pragma unroll
    for (int r = 0; r < 4; ++r) {
      float rs = __shfl_xor(o[r], 8, 64);
      float outv = o[r] * __builtin_amdgcn_rcpf(rs * C0);
      if (c < 8)
        orow[(16 * b + 4 * t + r) * ND + c] = f2bf(outv);
    }
  }
}

// ---------------- projection GEMM: y[M,N] = A[M,K] * Bt[N,K]^T ----------------
#define BM 128
#define BN 128
#define BK 32

__global__ __launch_bounds__(256) void gemm_kernel(const unsigned short* __restrict__ A,
                                                   const unsigned short* __restrict__ Bt,
                                                   float* __restrict__ C) {
  __shared__ __align__(16) unsigned short As[BM * BK];
  __shared__ __align__(16) unsigned short Bs[BN * BK];

  const int bm = blockIdx.x;
  const int bn = blockIdx.y;
  const int tid = (int)threadIdx.x;
  const int lane = tid & 63;
  const int w = tid >> 6;
  const int wm = w >> 1;
  const int wn = w & 1;

  f32x4 acc[4][4] = {};

  const int sr = w * 32 + (lane >> 2);
  const int sc = (lane & 3) * 8;
  const unsigned short* gA = A + (size_t)(bm * BM + sr) * GK + sc;
  const unsigned short* gB = Bt + (size_t)(bn * BN + sr) * GK + sc;
  unsigned short* lA = &As[(w * 32) * BK];
  unsigned short* lB = &Bs[(w * 32) * BK];

  const int fr = lane & 15;
  const int fk = (lane >> 4) * 8;

  for (int kt = 0; kt < GK; kt += BK) {
    __syncthreads();
    GLOAD_LDS16(gA, lA);
    GLOAD_LDS16(gA + 16 * GK, lA + 16 * BK);
    GLOAD_LDS16(gB, lB);
    GLOAD_LDS16(gB + 16 * GK, lB + 16 * BK);
    asm volatile("s_waitcnt vmcnt(0)" ::: "memory");
    __syncthreads();

    bf16x8 af[4], bfr[4];
#pragma unroll
    for (int i = 0; i < 4; ++i)
      af[i] = *reinterpret_cast<const bf16x8*>(&As[(wm * 64 + i * 16 + fr) * BK + fk]);
#pragma unroll
    for (int j = 0; j < 4; ++j)
      bfr[j] = *reinterpret_cast<const bf16x8*>(&Bs[(wn * 64 + j * 16 + fr) * BK + fk]);

#pragma unroll
    for (int i = 0; i < 4; ++i)
#pragma unroll
      for (int j = 0; j < 4; ++j)
        acc[i][j] = __builtin_amdgcn_mfma_f32_16x16x32_bf16(af[i], bfr[j], acc[i][j], 0, 0, 0);

    gA += BK;
    gB += BK;
  }

  float* Cb = C + (size_t)(bm * BM + wm * 64) * GN + bn * BN + wn * 64;
  const int cr = (lane >> 4) * 4;
  const int cc = lane & 15;
#pragma unroll
  for (int i = 0; i < 4; ++i)
#pragma unroll
    for (int j = 0; j < 4; ++j)
#pragma unroll
      for (int r = 0; r < 4; ++r)
        Cb[(size_t)(i * 16 + cr + r) * GN + j * 16 + cc] = acc[i][j][r];
}

extern "C" void kernel_launch(void* const* d_in, const int* in_sizes, int n_in,
                              void* d_out, int out_size, void* d_ws, size_t ws_size,
                              hipStream_t stream) {
  (void)in_sizes; (void)n_in; (void)out_size; (void)ws_size;
  const float* x = (const float*)d_in[0];
  const float* theta = (const float*)d_in[1];
  const float* wproj = (const float*)d_in[2];
  float* y = (float*)d_out;

  unsigned short* attn_out = (unsigned short*)d_ws;                            // 16 MB bf16
  unsigned short* wb = (unsigned short*)((char*)d_ws + (size_t)NTOK * NC * 2); // 2 MB bf16

  wconv_kernel<<<(NC * NC / 4) / 256, 256, 0, stream>>>((const float4*)wproj,
                                                        (ushort4*)wb);
  attn_kernel<<<NTOK / 4, 256, 0, stream>>>(x, theta, attn_out);
  dim3 grid(NTOK / BM, GN / BN);
  gemm_kernel<<<grid, 256, 0, stream>>>(attn_out, wb, y);
}

// Round 6
// 62.869 us; speedup vs baseline: 2.0835x; 1.1005x over previous
//
#include <hip/hip_runtime.h>
#include <hip/hip_bf16.h>
#include <stdint.h>

#define NB 4
#define NT 2048
#define NC 1024
#define NH 128
#define ND 8
#define NTOK (NB*NT)      // 8192 tokens
#define GK 1024           // GEMM K
#define GN 1024           // GEMM N

typedef __attribute__((ext_vector_type(4))) float f32x4;
typedef __attribute__((ext_vector_type(8))) short bf16x8;
typedef __attribute__((ext_vector_type(4))) unsigned int u32x4;
typedef __attribute__((ext_vector_type(2))) unsigned int u32x2;
typedef unsigned int uint32;

// GAMMA = sqrt(log2(e)/sqrt(8)) folded into q' so exp2(S) needs no scale:
//   S = (GAMMA*cos)·(GAMMA*cos) summed = log2(e)/sqrt(8) * qq  -> exp2(S) = exp(qq/sqrt(8)).
// GB16 = bf16 0x3F37 = 0.71484375: PV ones-column value carrying the rowsum.
// C0 = GAMMA / 0.71484375 corrects the output/rowsum scale ratio.
#define GAMMA  0.71419167f
#define GB16   0x3F37u
#define C0     0.9990878f

#define GLOAD_LDS16(g, l) \
  __builtin_amdgcn_global_load_lds((const __attribute__((address_space(1))) void*)(g), \
                                   (__attribute__((address_space(3))) void*)(l), 16, 0, 0)

__device__ __forceinline__ unsigned short f2bf(float f) {
  __bf16 b = (__bf16)f;
  return __builtin_bit_cast(unsigned short, b);
}
__device__ __forceinline__ uint32 pk2(float a, float b) {   // bf16 pair, a in low
  return (uint32)f2bf(a) | ((uint32)f2bf(b) << 16);
}

// ---------------- W fp32 -> bf16 ----------------
__global__ __launch_bounds__(256) void wconv_kernel(const float4* __restrict__ w,
                                                    ushort4* __restrict__ wb) {
  int i = blockIdx.x * 256 + threadIdx.x;
  float4 v = w[i];
  ushort4 o;
  o.x = f2bf(v.x); o.y = f2bf(v.y); o.z = f2bf(v.z); o.w = f2bf(v.w);
  wb[i] = o;
}

// ---- per-token attention: 1 wave/token, 16x16x32 MFMA only (verified maps) --
// Verified fragment maps (gemm_kernel + R2, both passed on HW):
//   A/B: lane l -> row/col l&15, k-slots (l>>4)*8 + e (e=0..7)
//   C/D: lane l reg r -> m=(l>>4)*4+r, n=l&15
// S-operands under sigma_S(8t+e)= 2t+e (e<2, else dead): lane (c,t) supplies
//   its own dims 2t,2t+1 of rows 16a+c -> S = full 8-dim dot, no cross-lane.
// S symmetric => S-block(a,b) reg r at lane(c,t) = P[16b+c][16a+4t+r]:
//   row = c = A-fragment row => packed p-pairs of blocks (2j,2j+1) ARE the
//   PV A-fragment under sigma_j(8t+e) = 32j + 4t + (e&3) + 16*(e>>2).
// PV B reads sigma_j-permuted QT rows from LDS; cols 8..15 = GB16 (rowsum).
#define QTS 136   // QT row stride (elements); 272B rows spread banks

__global__ __launch_bounds__(256) void attn_kernel(const float* __restrict__ x,
                                                   const float* __restrict__ theta,
                                                   unsigned short* __restrict__ aout) {
  __shared__ __align__(16) unsigned short QT[4][8 * QTS];   // 8704 B total

  const int tid = (int)threadIdx.x;
  const int wid = tid >> 6;
  const int tok = blockIdx.x * 4 + wid;
  const int l = tid & 63;
  const int c = l & 15;
  const int t = l >> 4;

  float S = 0.f;
#pragma unroll
  for (int j = 0; j < ND; ++j) S += theta[j];

  // Load x: lane (c,t) owns rows 16a+c, dims 2t,2t+1 (wave tiles 512B/a).
  // q' = GAMMA*cos(x+S) -> S-fragment word0; QT[dim][g] for the PV B side.
  u32x4 qf[8];
  unsigned short* qt = &QT[wid][0];
#pragma unroll
  for (int a = 0; a < 8; ++a) {
    float2 xv = *(const float2*)(x + (size_t)tok * NC + (16 * a + c) * ND + 2 * t);
    float q0 = GAMMA * __cosf(xv.x + S);
    float q1 = GAMMA * __cosf(xv.y + S);
    unsigned short b0 = f2bf(q0), b1 = f2bf(q1);
    qt[(2 * t) * QTS + 16 * a + c] = b0;
    qt[(2 * t + 1) * QTS + 16 * a + c] = b1;
    qf[a].x = (uint32)b0 | ((uint32)b1 << 16);
    qf[a].y = 0u; qf[a].z = 0u; qf[a].w = 0u;
  }

  // PV B-fragments (shared by all 8 row-blocks): element e of frag j =
  //   Vext[32j + 4t + (e&3) + 16*(e>>2)][c];  cols c>=8 -> GB16 ones.
  u32x4 bff[4];
  {
    const int cm = (c < 8) ? c : 7;
    const bool isq = (c < 8);
    const uint32 onepair = GB16 | (GB16 << 16);
#pragma unroll
    for (int j = 0; j < 4; ++j) {
      u32x2 v0 = *(const u32x2*)&qt[cm * QTS + 32 * j + 4 * t];
      u32x2 v1 = *(const u32x2*)&qt[cm * QTS + 32 * j + 16 + 4 * t];
      bff[j].x = isq ? v0.x : onepair;
      bff[j].y = isq ? v0.y : onepair;
      bff[j].z = isq ? v1.x : onepair;
      bff[j].w = isq ? v1.y : onepair;
    }
  }

  const f32x4 z4 = {0.f, 0.f, 0.f, 0.f};
  unsigned short* orow = aout + (size_t)tok * NC;

#pragma unroll
  for (int b = 0; b < 8; ++b) {        // P-row block: rows 16b..16b+15
    f32x4 o = z4;
#pragma unroll
    for (int j = 0; j < 4; ++j) {      // g-chunk 32j..32j+31
      f32x4 sv0 = __builtin_amdgcn_mfma_f32_16x16x32_bf16(
          __builtin_bit_cast(bf16x8, qf[2 * j]), __builtin_bit_cast(bf16x8, qf[b]),
          z4, 0, 0, 0);
      f32x4 sv1 = __builtin_amdgcn_mfma_f32_16x16x32_bf16(
          __builtin_bit_cast(bf16x8, qf[2 * j + 1]), __builtin_bit_cast(bf16x8, qf[b]),
          z4, 0, 0, 0);
      // p = exp2(S); lane(c,t) reg r: sv0 -> P[16b+c][32j+4t+r],
      //                               sv1 -> P[16b+c][32j+16+4t+r]
      u32x4 af;
      af.x = pk2(__builtin_amdgcn_exp2f(sv0[0]), __builtin_amdgcn_exp2f(sv0[1]));
      af.y = pk2(__builtin_amdgcn_exp2f(sv0[2]), __builtin_amdgcn_exp2f(sv0[3]));
      af.z = pk2(__builtin_amdgcn_exp2f(sv1[0]), __builtin_amdgcn_exp2f(sv1[1]));
      af.w = pk2(__builtin_amdgcn_exp2f(sv1[2]), __builtin_amdgcn_exp2f(sv1[3]));
      o = __builtin_amdgcn_mfma_f32_16x16x32_bf16(
          __builtin_bit_cast(bf16x8, af), __builtin_bit_cast(bf16x8, bff[j]),
          o, 0, 0, 0);
    }
    // o reg r = O'[16b+4t+r][c]; rowsum*GB16 sits at col c+8 (lane l^8, same reg)
#pragma unroll
    for (int r = 0; r < 4; ++r) {
      float rs = __shfl_xor(o[r], 8, 64);
      float outv = o[r] * __builtin_amdgcn_rcpf(rs * C0);
      if (c < 8)
        orow[(16 * b + 4 * t + r) * ND + c] = f2bf(outv);
    }
  }
}

// ---------------- projection GEMM: y[M,N] = A[M,K] * Bt[N,K]^T ----------------
// 128x128 tile, BK=64, 8 waves (2x4), double-buffered LDS (64 KB -> exactly
// 2 blocks/CU, grid 512 = one residency shift). Prefetch pipeline: issue next
// tile's global_load_lds BEFORE compute, counted s_waitcnt vmcnt(4) + raw
// s_barrier (no __syncthreads -> no compiler vmcnt(0) drain). Chunk-XOR
// swizzle (rule #21): linear LDS dest, inverse-swizzled GLOBAL source,
// swizzled read slot kc^(row&7) -> 2-way banks on ds_read_b128 (free).
#define BM 128
#define BN 128
#define BK 64

__global__ __launch_bounds__(512, 4) void gemm_kernel(const unsigned short* __restrict__ A,
                                                      const unsigned short* __restrict__ Bt,
                                                      float* __restrict__ C) {
  __shared__ __align__(16) unsigned short As[2][BM * BK];  // 2 x 16 KB
  __shared__ __align__(16) unsigned short Bs[2][BN * BK];  // 2 x 16 KB

  const int bm = blockIdx.x;
  const int bn = blockIdx.y;
  const int tid = (int)threadIdx.x;
  const int l = tid & 63;
  const int w = tid >> 6;        // wave 0..7
  const int wm = w >> 2;         // 0..1 over M (64-row halves)
  const int wn = w & 3;          // 0..3 over N (32-col quarters)

  f32x4 acc[4][2] = {};

  // --- staging addresses: wave w covers rows 16w..16w+15 of A and of B ---
  const int srow = l >> 3;                   // 0..7 within 8-row group
  const int schk = (l & 7) ^ srow;           // inverse-swizzled source chunk
  const unsigned short* gA0 = A + (size_t)(bm * BM + 16 * w + srow) * GK + schk * 8;
  const unsigned short* gA1 = gA0 + 8 * GK;
  const unsigned short* gB0 = Bt + (size_t)(bn * BN + 16 * w + srow) * GK + schk * 8;
  const unsigned short* gB1 = gB0 + 8 * GK;

  const int fr = l & 15;                     // fragment row
  const int kcb = l >> 4;                    // k-chunk base (0..3)
  const int fx = l & 7;                      // row-XOR for swizzled read

#define STAGE(nb)                                          \
  {                                                        \
    unsigned short* la = &As[nb][(16 * w) * BK];           \
    unsigned short* lb = &Bs[nb][(16 * w) * BK];           \
    GLOAD_LDS16(gA0, la);                                  \
    GLOAD_LDS16(gA1, la + 8 * BK);                         \
    GLOAD_LDS16(gB0, lb);                                  \
    GLOAD_LDS16(gB1, lb + 8 * BK);                         \
    gA0 += BK; gA1 += BK; gB0 += BK; gB1 += BK;            \
  }

  auto compute = [&](const unsigned short* as, const unsigned short* bs) {
#pragma unroll
    for (int s = 0; s < 2; ++s) {            // k-halves of BK=64
      const int slot = ((4 * s + kcb) ^ fx) * 8;
      bf16x8 af[4], bfr[2];
#pragma unroll
      for (int i = 0; i < 4; ++i)
        af[i] = *reinterpret_cast<const bf16x8*>(&as[(64 * wm + 16 * i + fr) * BK + slot]);
#pragma unroll
      for (int j = 0; j < 2; ++j)
        bfr[j] = *reinterpret_cast<const bf16x8*>(&bs[(32 * wn + 16 * j + fr) * BK + slot]);
#pragma unroll
      for (int i = 0; i < 4; ++i)
#pragma unroll
        for (int j = 0; j < 2; ++j)
          acc[i][j] = __builtin_amdgcn_mfma_f32_16x16x32_bf16(af[i], bfr[j], acc[i][j], 0, 0, 0);
    }
  };

  // prologue: tile 0 -> buf 0
  STAGE(0);

  int buf = 0;
#pragma unroll 1
  for (int t = 0; t < 15; ++t) {
    STAGE(buf ^ 1);                          // issue next tile first
    asm volatile("s_waitcnt vmcnt(4)" ::: "memory");   // current tile landed
    __builtin_amdgcn_s_barrier();
    asm volatile("" ::: "memory");
    compute(&As[buf][0], &Bs[buf][0]);
    asm volatile("" ::: "memory");
    __builtin_amdgcn_s_barrier();            // reads done before next overwrite
    asm volatile("" ::: "memory");
    buf ^= 1;
  }
  asm volatile("s_waitcnt vmcnt(0)" ::: "memory");
  __builtin_amdgcn_s_barrier();
  asm volatile("" ::: "memory");
  compute(&As[1][0], &Bs[1][0]);

  // C/D layout: col = lane&15, row = (lane>>4)*4 + reg  [m89/m91 verified]
  float* Cb = C + (size_t)(bm * BM + 64 * wm) * GN + bn * BN + 32 * wn;
  const int cr = (l >> 4) * 4;
  const int cc = l & 15;
#pragma unroll
  for (int i = 0; i < 4; ++i)
#pragma unroll
    for (int j = 0; j < 2; ++j)
#pragma unroll
      for (int r = 0; r < 4; ++r)
        Cb[(size_t)(16 * i + cr + r) * GN + 16 * j + cc] = acc[i][j][r];
#undef STAGE
}

extern "C" void kernel_launch(void* const* d_in, const int* in_sizes, int n_in,
                              void* d_out, int out_size, void* d_ws, size_t ws_size,
                              hipStream_t stream) {
  (void)in_sizes; (void)n_in; (void)out_size; (void)ws_size;
  const float* x = (const float*)d_in[0];
  const float* theta = (const float*)d_in[1];
  const float* wproj = (const float*)d_in[2];
  float* y = (float*)d_out;

  unsigned short* attn_out = (unsigned short*)d_ws;                            // 16 MB bf16
  unsigned short* wb = (unsigned short*)((char*)d_ws + (size_t)NTOK * NC * 2); // 2 MB bf16

  wconv_kernel<<<(NC * NC / 4) / 256, 256, 0, stream>>>((const float4*)wproj,
                                                        (ushort4*)wb);
  attn_kernel<<<NTOK / 4, 256, 0, stream>>>(x, theta, attn_out);
  dim3 grid(NTOK / BM, GN / BN);
  gemm_kernel<<<grid, 512, 0, stream>>>(attn_out, wb, y);
}